// Round 6
// baseline (721.045 us; speedup 1.0000x reference)
//
#include <hip/hip_runtime.h>

typedef unsigned short u16;
typedef unsigned int u32;
typedef __bf16 bf16x8 __attribute__((ext_vector_type(8)));
typedef float f32x4 __attribute__((ext_vector_type(4)));

#define NEG_MAX 3.402823466e38f

__device__ __forceinline__ float b2f(u16 u){
  union { float f; u32 i; } v; v.i = ((u32)u) << 16; return v.f;
}
__device__ __forceinline__ u16 f2bu(float f){
  u32 u = __float_as_uint(f);
  u32 r = (u + 0x7fffu + ((u >> 16) & 1u)) >> 16;
  return (u16)r;
}

// ---------------------------------------------------------------------------
// prep2: WcT[d][n] = Wp[n][d] + 1e-5*Wm[n][d]  (f32, 300x300, transposed)
//        bc[n]    = bp[n] + 1e-5*bm[n]
// ---------------------------------------------------------------------------
__global__ __launch_bounds__(256) void prep2_kernel(
    const float* __restrict__ Wp, const float* __restrict__ bp,
    const float* __restrict__ Wm, const float* __restrict__ bm,
    float* __restrict__ WcT, float* __restrict__ bc)
{
  int idx = blockIdx.x * 256 + threadIdx.x;
  if (idx < 90000) {
    int n = idx % 300, d = idx / 300;
    WcT[idx] = Wp[n * 300 + d] + 1e-5f * Wm[n * 300 + d];
    if (idx < 300) bc[idx] = bp[idx] + 1e-5f * bm[idx];
  }
}

// ---------------------------------------------------------------------------
// gemm0 (MFMA): k_emb[m][n] = sum_k feature[m][k]*Wf[n][k] + bf[n]
//                             + wv[label[m]][n]        -> f32 out
// f32 sources converted to bf16 during LDS staging. 128x128 tile, 4 waves,
// 16x16x32 bf16 MFMA. A-frag A[m=lane&15][k=(lane>>4)*8+j]; B operand given
// Bt[n=lane&15][k] == B[k][n]; C/D col=lane&15, row=(lane>>4)*4+reg.
// ---------------------------------------------------------------------------
__global__ __launch_bounds__(256) void gemm0_kernel(
    const float* __restrict__ A, const float* __restrict__ B,
    const float* __restrict__ bias,
    const int* __restrict__ label, const float* __restrict__ wv,
    float* __restrict__ C)
{
  __shared__ __align__(16) u16 As[128 * 32];
  __shared__ __align__(16) u16 Bs[128 * 32];
  const int lda = 2048, ldb = 2048, K = 2048, nbn = 3, nsrc = 300;
  int t = threadIdx.x;
  int bm = (blockIdx.x / nbn) * 128;
  int bn = (blockIdx.x % nbn) * 128;
  int lane = t & 63, w = t >> 6;
  int wm = (w >> 1) * 64, wn = (w & 1) * 64;

  f32x4 acc[4][4];
  for (int i = 0; i < 4; i++)
    for (int j = 0; j < 4; j++)
      for (int r = 0; r < 4; r++) acc[i][j][r] = 0.f;

  int mrow = lane & 15, q = lane >> 4;

  for (int kk = 0; kk < K; kk += 32) {
    #pragma unroll
    for (int p = 0; p < 2; p++) {
      int idx = t + p * 256;
      int row = idx >> 2, ch = idx & 3;
      int brow = bn + row;
      if (brow >= nsrc) brow = 0;  // clamp; masked at store
      const float4* ap = (const float4*)&A[(size_t)(bm + row) * lda + kk + ch * 8];
      float4 a0 = ap[0], a1 = ap[1];
      const float4* bp_ = (const float4*)&B[(size_t)brow * ldb + kk + ch * 8];
      float4 b0 = bp_[0], b1 = bp_[1];
      union { u16 h[8]; uint4 v; } pa, pb;
      pa.h[0] = f2bu(a0.x); pa.h[1] = f2bu(a0.y);
      pa.h[2] = f2bu(a0.z); pa.h[3] = f2bu(a0.w);
      pa.h[4] = f2bu(a1.x); pa.h[5] = f2bu(a1.y);
      pa.h[6] = f2bu(a1.z); pa.h[7] = f2bu(a1.w);
      pb.h[0] = f2bu(b0.x); pb.h[1] = f2bu(b0.y);
      pb.h[2] = f2bu(b0.z); pb.h[3] = f2bu(b0.w);
      pb.h[4] = f2bu(b1.x); pb.h[5] = f2bu(b1.y);
      pb.h[6] = f2bu(b1.z); pb.h[7] = f2bu(b1.w);
      *(uint4*)&As[idx * 8] = pa.v;
      *(uint4*)&Bs[idx * 8] = pb.v;
    }
    __syncthreads();

    bf16x8 af[4], bfr[4];
    #pragma unroll
    for (int i = 0; i < 4; i++)
      af[i] = *(const bf16x8*)&As[(wm + i * 16 + mrow) * 32 + q * 8];
    #pragma unroll
    for (int j = 0; j < 4; j++)
      bfr[j] = *(const bf16x8*)&Bs[(wn + j * 16 + mrow) * 32 + q * 8];
    #pragma unroll
    for (int i = 0; i < 4; i++)
      #pragma unroll
      for (int j = 0; j < 4; j++)
        acc[i][j] = __builtin_amdgcn_mfma_f32_16x16x32_bf16(
            af[i], bfr[j], acc[i][j], 0, 0, 0);
    __syncthreads();
  }

  #pragma unroll
  for (int i = 0; i < 4; i++)
    #pragma unroll
    for (int j = 0; j < 4; j++) {
      int col = bn + wn + j * 16 + (lane & 15);
      if (col >= 300) continue;
      int rb = bm + wm + i * 16 + (lane >> 4) * 4;
      #pragma unroll
      for (int r = 0; r < 4; r++) {
        int m = rb + r;
        float v = acc[i][j][r];
        v += bias[col] + wv[(size_t)label[m] * 300 + col];
        C[(size_t)m * 300 + col] = v;   // f32 store
      }
    }
}

// ---------------------------------------------------------------------------
// attn + projection fused: one block per (b,y) row.
// k_emb[b] staged f32->bf16 into LDS (38.4KB); q_emb (12x300 f32) gathered.
// att -> 1/sum identity -> mask -> word softmax/5 -> p_raw (LDS f32)
// -> p_emb[n] = bc[n] + sum_d p_raw[d]*WcT[d][n]   (f32 out)
// ---------------------------------------------------------------------------
__global__ __launch_bounds__(256) void attn_proj_kernel(
    const float* __restrict__ wv, const int* __restrict__ query,
    const float* __restrict__ kemb, const float* __restrict__ WcT,
    const float* __restrict__ bc, float* __restrict__ p_out)
{
  __shared__ __align__(16) u16 ke[64 * 300];
  __shared__ __align__(16) float qe[12 * 300];
  __shared__ __align__(16) float att[12 * 64];
  __shared__ __align__(16) float ps[300];
  __shared__ __align__(16) float qma[12];
  __shared__ __align__(16) float wt[12];
  __shared__ __align__(16) int qidx[12];

  int row = blockIdx.x;            // b*32 + y
  int b = row >> 5;
  int t = threadIdx.x;

  // stage k_emb[b]: 64x300 f32 -> bf16 LDS (4800 float4 -> ushort4)
  {
    const float4* src = (const float4*)(kemb + (size_t)b * 19200);
    ushort4* dst = (ushort4*)ke;
    for (int i = t; i < 4800; i += 256) {
      float4 v = src[i];
      ushort4 o;
      o.x = f2bu(v.x); o.y = f2bu(v.y); o.z = f2bu(v.z); o.w = f2bu(v.w);
      dst[i] = o;
    }
  }
  if (t < 12) qidx[t] = query[row * 12 + t];
  __syncthreads();

  // gather q_emb rows: 12 x 75 float4
  {
    float4* qe4w = (float4*)qe;
    const float4* wv4 = (const float4*)wv;
    for (int e = t; e < 900; e += 256) {
      int w = e / 75, d = e % 75;
      qe4w[w * 75 + d] = wv4[(size_t)qidx[w] * 75 + d];
    }
  }
  __syncthreads();

  const ushort4* ke4 = (const ushort4*)ke;
  const float4* qe4 = (const float4*)qe;
  int k = t & 63;
  int wbase = t >> 6;
  #pragma unroll
  for (int pass = 0; pass < 3; pass++) {
    int w = pass * 4 + wbase;
    float s = 0.f;
    for (int d = 0; d < 75; d++) {
      float4 qv = qe4[w * 75 + d];
      ushort4 kv = ke4[k * 75 + d];
      s += qv.x * b2f(kv.x) + qv.y * b2f(kv.y) +
           qv.z * b2f(kv.z) + qv.w * b2f(kv.w);
    }
    att[w * 64 + k] = s * 0.0577350269189626f;  // 1/sqrt(300)
  }
  __syncthreads();

  if (t < 12) {
    float m = -NEG_MAX;
    for (int k2 = 0; k2 < 64; k2++) m = fmaxf(m, att[t * 64 + k2]);
    float s = 0.f;
    for (int k2 = 0; k2 < 64; k2++) s += expf(att[t * 64 + k2] - m);
    float a = 1.0f / s;  // == max_k softmax(att)
    qma[t] = (qidx[t] == 0) ? -NEG_MAX : a;
  }
  __syncthreads();
  if (t == 0) {
    float m2 = -NEG_MAX;
    for (int w = 0; w < 12; w++) m2 = fmaxf(m2, qma[w]);
    float e[12], s2 = 0.f;
    for (int w = 0; w < 12; w++) { e[w] = expf(qma[w] - m2); s2 += e[w]; }
    float inv = 0.2f / s2;
    for (int w = 0; w < 12; w++) wt[w] = e[w] * inv;
  }
  __syncthreads();

  // p_raw into LDS (f32)
  if (t < 75) {
    float ax = 0.f, ay = 0.f, az = 0.f, aw = 0.f;
    for (int w = 0; w < 12; w++) {
      float4 qv = qe4[w * 75 + t];
      float g = wt[w];
      ax += g * qv.x; ay += g * qv.y;
      az += g * qv.z; aw += g * qv.w;
    }
    float4 o; o.x = ax; o.y = ay; o.z = az; o.w = aw;
    ((float4*)ps)[t] = o;
  }
  __syncthreads();

  // projection: p_emb[row][n] = bc[n] + sum_d ps[d]*WcT[d*300+n]  (f32 out)
  for (int n = t; n < 300; n += 256) {
    float acc = bc[n];
    for (int d = 0; d < 300; d++)
      acc = fmaf(ps[d], WcT[d * 300 + n], acc);
    p_out[(size_t)row * 300 + n] = acc;
  }
}

// ---------------------------------------------------------------------------
extern "C" void kernel_launch(void* const* d_in, const int* in_sizes, int n_in,
                              void* d_out, int out_size, void* d_ws,
                              size_t ws_size, hipStream_t stream)
{
  const float* wv      = (const float*)d_in[0];   // [30000,300] f32
  const float* Wf      = (const float*)d_in[1];   // [300,2048]  f32
  const float* bf      = (const float*)d_in[2];   // [300]       f32
  const float* Wp      = (const float*)d_in[3];   // [300,300]   f32
  const float* bp      = (const float*)d_in[4];   // [300]       f32
  const float* Wm      = (const float*)d_in[5];   // [300,300]   f32
  const float* bm      = (const float*)d_in[6];   // [300]       f32
  const float* feature = (const float*)d_in[7];   // [256,64,2048] f32
  const int*   query   = (const int*)d_in[8];     // [256,32,12]
  const int*   label   = (const int*)d_in[9];     // [256,64]

  float* out   = (float*)d_out;     // f32 output (reference dtype)
  float* p_out = out;               // p_emb: 8192*300 f32
  float* k_out = out + 2457600;     // k_emb: 16384*300 f32

  char* ws   = (char*)d_ws;
  float* WcT = (float*)ws;               // 300*300 f32
  float* bc  = (float*)(ws + 360448);    // 300 f32

  prep2_kernel<<<352, 256, 0, stream>>>(Wp, bp, Wm, bm, WcT, bc);

  // k_emb: M=16384, N=300 (pad 384), K=2048
  gemm0_kernel<<<128 * 3, 256, 0, stream>>>(feature, Wf, bf, label, wv, k_out);

  attn_proj_kernel<<<8192, 256, 0, stream>>>(wv, query, k_out, WcT, bc, p_out);
}

// Round 7
// 376.689 us; speedup vs baseline: 1.9142x; 1.9142x over previous
//
#include <hip/hip_runtime.h>

typedef unsigned short u16;
typedef unsigned int u32;
typedef __bf16 bf16x8 __attribute__((ext_vector_type(8)));
typedef float f32x4 __attribute__((ext_vector_type(4)));

#if defined(__has_builtin)
#  if __has_builtin(__builtin_amdgcn_cvt_pk_bf16_f32)
#    define PK_BF16 1
#  endif
#endif

__device__ __forceinline__ u16 f2bu(float f){
  u32 u = __float_as_uint(f);
  return (u16)((u + 0x7fffu + ((u >> 16) & 1u)) >> 16);
}
__device__ __forceinline__ float b2f(u16 u){
  union { float f; u32 i; } v; v.i = ((u32)u) << 16; return v.f;
}
__device__ __forceinline__ u32 pkbf(float a, float b){
#ifdef PK_BF16
  typedef __bf16 bf16x2 __attribute__((ext_vector_type(2)));
  union { bf16x2 h; u32 u; } c;
  c.h = __builtin_amdgcn_cvt_pk_bf16_f32(a, b);
  return c.u;
#else
  return (u32)f2bu(a) | ((u32)f2bu(b) << 16);
#endif
}

// ---------------------------------------------------------------------------
// prep_wc: Wc[384][320] bf16 = Wp + 1e-5*Wm (zero padded), bc[384] f32
// ---------------------------------------------------------------------------
__global__ __launch_bounds__(256) void prep_wc(
    const float* __restrict__ Wp, const float* __restrict__ bp,
    const float* __restrict__ Wm, const float* __restrict__ bm,
    u16* __restrict__ Wc, float* __restrict__ bc)
{
  int idx = blockIdx.x * 256 + threadIdx.x;   // bf16-pair index
  if (idx < 384 * 160) {
    int n = idx / 160, k = (idx % 160) * 2;
    float v0 = 0.f, v1 = 0.f;
    if (n < 300 && k < 300) {          // k even, 300 even -> k+1 < 300 too
      v0 = Wp[n * 300 + k]     + 1e-5f * Wm[n * 300 + k];
      v1 = Wp[n * 300 + k + 1] + 1e-5f * Wm[n * 300 + k + 1];
    }
    ((u32*)Wc)[idx] = pkbf(v0, v1);
    if (idx < 384) bc[idx] = (idx < 300) ? bp[idx] + 1e-5f * bm[idx] : 0.f;
  }
}

// ---------------------------------------------------------------------------
// prep_wv16: wv16[30000][320] bf16 copy of wv (cols 300..319 zero)
// ---------------------------------------------------------------------------
__global__ __launch_bounds__(256) void prep_wv16(
    const float* __restrict__ wv, u16* __restrict__ wv16)
{
  int idx = blockIdx.x * 256 + threadIdx.x;   // pair index
  if (idx < 30000 * 160) {
    int row = idx / 160, k = (idx % 160) * 2;
    float v0 = 0.f, v1 = 0.f;
    if (k < 300) {
      v0 = wv[(size_t)row * 300 + k];
      v1 = wv[(size_t)row * 300 + k + 1];
    }
    ((u32*)wv16)[idx] = pkbf(v0, v1);
  }
}

// ---------------------------------------------------------------------------
// gemm0 (MFMA): k_emb[m][n] = sum_k feature[m][k]*Wf[n][k] + bf[n]
//               + wv[label[m]][n]  -> f32 k_out (+ optional bf16 kemb16)
// 128x128 tile, 4 waves, 16x16x32 bf16 MFMA; f32->bf16 cvt in staging.
// ---------------------------------------------------------------------------
__global__ __launch_bounds__(256) void gemm0_kernel(
    const float* __restrict__ A, const float* __restrict__ B,
    const float* __restrict__ bias,
    const int* __restrict__ label, const float* __restrict__ wv,
    float* __restrict__ C, u16* __restrict__ kemb16)
{
  __shared__ __align__(16) u16 As[128 * 32];
  __shared__ __align__(16) u16 Bs[128 * 32];
  const int lda = 2048, ldb = 2048, K = 2048, nbn = 3, nsrc = 300;
  int t = threadIdx.x;
  int bm = (blockIdx.x / nbn) * 128;
  int bn = (blockIdx.x % nbn) * 128;
  int lane = t & 63, w = t >> 6;
  int wm = (w >> 1) * 64, wn = (w & 1) * 64;

  f32x4 acc[4][4];
  for (int i = 0; i < 4; i++)
    for (int j = 0; j < 4; j++)
      for (int r = 0; r < 4; r++) acc[i][j][r] = 0.f;

  int mrow = lane & 15, q = lane >> 4;

  for (int kk = 0; kk < K; kk += 32) {
    #pragma unroll
    for (int p = 0; p < 2; p++) {
      int idx = t + p * 256;
      int row = idx >> 2, ch = idx & 3;
      int brow = bn + row;
      if (brow >= nsrc) brow = 0;  // clamp; masked at store
      const float4* ap = (const float4*)&A[(size_t)(bm + row) * lda + kk + ch * 8];
      float4 a0 = ap[0], a1 = ap[1];
      const float4* bpp = (const float4*)&B[(size_t)brow * ldb + kk + ch * 8];
      float4 b0 = bpp[0], b1 = bpp[1];
      union { u32 u[4]; uint4 v; } pa, pb;
      pa.u[0] = pkbf(a0.x, a0.y); pa.u[1] = pkbf(a0.z, a0.w);
      pa.u[2] = pkbf(a1.x, a1.y); pa.u[3] = pkbf(a1.z, a1.w);
      pb.u[0] = pkbf(b0.x, b0.y); pb.u[1] = pkbf(b0.z, b0.w);
      pb.u[2] = pkbf(b1.x, b1.y); pb.u[3] = pkbf(b1.z, b1.w);
      *(uint4*)&As[idx * 8] = pa.v;
      *(uint4*)&Bs[idx * 8] = pb.v;
    }
    __syncthreads();

    bf16x8 af[4], bfr[4];
    #pragma unroll
    for (int i = 0; i < 4; i++)
      af[i] = *(const bf16x8*)&As[(wm + i * 16 + mrow) * 32 + q * 8];
    #pragma unroll
    for (int j = 0; j < 4; j++)
      bfr[j] = *(const bf16x8*)&Bs[(wn + j * 16 + mrow) * 32 + q * 8];
    #pragma unroll
    for (int i = 0; i < 4; i++)
      #pragma unroll
      for (int j = 0; j < 4; j++)
        acc[i][j] = __builtin_amdgcn_mfma_f32_16x16x32_bf16(
            af[i], bfr[j], acc[i][j], 0, 0, 0);
    __syncthreads();
  }

  // epilogue: C/D layout col=lane&15, row=(lane>>4)*4+reg
  #pragma unroll
  for (int i = 0; i < 4; i++)
    #pragma unroll
    for (int j = 0; j < 4; j++) {
      int col = bn + wn + j * 16 + (lane & 15);
      int rb = bm + wm + i * 16 + (lane >> 4) * 4;
      #pragma unroll
      for (int r = 0; r < 4; r++) {
        int m = rb + r;
        if (col < 300) {
          float v = acc[i][j][r];
          v += bias[col] + wv[(size_t)label[m] * 300 + col];
          C[(size_t)m * 300 + col] = v;
          if (kemb16) kemb16[(size_t)m * 320 + col] = f2bu(v);
        } else if (kemb16 && col < 320) {
          kemb16[(size_t)m * 320 + col] = 0;
        }
      }
    }
}

// ---------------------------------------------------------------------------
// attn (MFMA): block = (b, half of 16 y) -> 192 qwords x 64 keys, K=320.
// ke (bf16) in LDS row-stride 328 (bank-conflict-free); A gathered per lane
// straight from wv16 (FULL) or wv f32 with cvt (fallback).
// softmax-over-keys via in-register shfl reductions (1/sum-exp identity),
// word-softmax/5, then p_raw gather-sum -> praw bf16 [row][320].
// ---------------------------------------------------------------------------
template <int FULL>
__global__ __launch_bounds__(256) void attn_kernel(
    const float* __restrict__ wv, const u16* __restrict__ wv16,
    const int* __restrict__ query,
    const float* __restrict__ kout, const u16* __restrict__ kemb16,
    u16* __restrict__ praw)
{
  __shared__ __align__(16) u16 ke[64 * 328];
  __shared__ __align__(16) int qoff[192];
  __shared__ __align__(16) float awd[192];
  __shared__ __align__(16) float wt[192];

  int blk = blockIdx.x, b = blk >> 1, bh = blk & 1;
  int t = threadIdx.x;
  int lane = t & 63, w = t >> 6;

  // stage ke: 64 rows x 320 bf16, LDS stride 328
  if (FULL) {
    for (int i = t; i < 2560; i += 256) {          // uint4 chunks of 8 cols
      int row = i / 40, ch = i % 40;
      *(uint4*)&ke[row * 328 + ch * 8] =
          *(const uint4*)&kemb16[(size_t)(b * 64 + row) * 320 + ch * 8];
    }
  } else {
    for (int i = t; i < 4800; i += 256) {          // float4 chunks of 4 cols
      int row = i / 75, c4 = i % 75;
      float4 v = *(const float4*)&kout[(size_t)(b * 64 + row) * 300 + c4 * 4];
      *(u32*)&ke[row * 328 + c4 * 4]     = pkbf(v.x, v.y);
      *(u32*)&ke[row * 328 + c4 * 4 + 2] = pkbf(v.z, v.w);
    }
    for (int i = t; i < 640; i += 256) {           // zero cols 300..319
      int row = i / 10, c2 = i % 10;
      *(u32*)&ke[row * 328 + 300 + c2 * 2] = 0;
    }
  }
  if (t < 192)
    qoff[t] = query[b * 384 + bh * 192 + t] * (FULL ? 320 : 300);
  __syncthreads();

  int mrow = lane & 15, q = lane >> 4;
  f32x4 acc[3][4];
  #pragma unroll
  for (int i = 0; i < 3; i++)
    #pragma unroll
    for (int j = 0; j < 4; j++)
      #pragma unroll
      for (int r = 0; r < 4; r++) acc[i][j][r] = 0.f;

  int base[3];
  #pragma unroll
  for (int i = 0; i < 3; i++) base[i] = qoff[w * 48 + i * 16 + mrow];
  int keb = mrow * 328 + q * 8;

  for (int k0 = 0; k0 < 320; k0 += 32) {
    bf16x8 af[3], bfr[4];
    #pragma unroll
    for (int i = 0; i < 3; i++) {
      if (FULL) {
        af[i] = *(const bf16x8*)&wv16[(size_t)base[i] + k0 + q * 8];
      } else {
        int cs = k0 + q * 8;
        union { u32 u[4]; bf16x8 h; } c;
        if (cs + 8 <= 300) {
          const float4* p = (const float4*)&wv[(size_t)base[i] + cs];
          float4 x = p[0], y = p[1];
          c.u[0] = pkbf(x.x, x.y); c.u[1] = pkbf(x.z, x.w);
          c.u[2] = pkbf(y.x, y.y); c.u[3] = pkbf(y.z, y.w);
        } else if (cs < 300) {   // cs == 296
          float4 x = *(const float4*)&wv[(size_t)base[i] + 296];
          c.u[0] = pkbf(x.x, x.y); c.u[1] = pkbf(x.z, x.w);
          c.u[2] = 0; c.u[3] = 0;
        } else {
          c.u[0] = 0; c.u[1] = 0; c.u[2] = 0; c.u[3] = 0;
        }
        af[i] = c.h;
      }
    }
    #pragma unroll
    for (int j = 0; j < 4; j++)
      bfr[j] = *(const bf16x8*)&ke[j * 16 * 328 + keb + k0];
    #pragma unroll
    for (int i = 0; i < 3; i++)
      #pragma unroll
      for (int j = 0; j < 4; j++)
        acc[i][j] = __builtin_amdgcn_mfma_f32_16x16x32_bf16(
            af[i], bfr[j], acc[i][j], 0, 0, 0);
  }

  // per-word softmax-over-keys: a_w = 1/sum_k exp(scale*(att-max))
  const float scale = 0.05773502691896258f;   // 1/sqrt(300)
  #pragma unroll
  for (int i = 0; i < 3; i++)
    #pragma unroll
    for (int r = 0; r < 4; r++) {
      float mx = fmaxf(fmaxf(acc[i][0][r], acc[i][1][r]),
                       fmaxf(acc[i][2][r], acc[i][3][r]));
      #pragma unroll
      for (int d = 1; d < 16; d <<= 1)
        mx = fmaxf(mx, __shfl_xor(mx, d));
      float se = 0.f;
      #pragma unroll
      for (int j = 0; j < 4; j++)
        se += __expf((acc[i][j][r] - mx) * scale);
      #pragma unroll
      for (int d = 1; d < 16; d <<= 1)
        se += __shfl_xor(se, d);
      if (mrow == 0) {
        int wl = w * 48 + i * 16 + q * 4 + r;
        awd[wl] = (qoff[wl] == 0) ? -3.402823466e38f : (1.0f / se);
      }
    }
  __syncthreads();

  // per-y softmax over 12 words, /5
  if (t < 16) {
    int yb = t * 12;
    float m2 = -3.402823466e38f;
    for (int i = 0; i < 12; i++) m2 = fmaxf(m2, awd[yb + i]);
    float e[12], s2 = 0.f;
    for (int i = 0; i < 12; i++) { e[i] = __expf(awd[yb + i] - m2); s2 += e[i]; }
    float inv = 0.2f / s2;
    for (int i = 0; i < 12; i++) wt[yb + i] = e[i] * inv;
  }
  __syncthreads();

  // p_raw: wave w handles 4 y's; lane covers d in 5 chunks of 64
  #pragma unroll
  for (int yy = 0; yy < 4; yy++) {
    int yl = w * 4 + yy;
    int row = b * 32 + bh * 16 + yl;
    #pragma unroll
    for (int c = 0; c < 5; c++) {
      int d = c * 64 + lane;
      float s = 0.f;
      if (d < 300) {
        for (int i = 0; i < 12; i++) {
          float g = wt[yl * 12 + i];
          int off = qoff[yl * 12 + i];
          s += g * (FULL ? b2f(wv16[(size_t)off + d]) : wv[(size_t)off + d]);
        }
      }
      praw[(size_t)row * 320 + d] = f2bu(s);
    }
  }
}

// ---------------------------------------------------------------------------
// proj (MFMA): p_emb[8192][300] = praw(bf16) @ Wc(bf16)^T + bc -> f32
// ---------------------------------------------------------------------------
__global__ __launch_bounds__(256) void proj_kernel(
    const u16* __restrict__ praw, const u16* __restrict__ Wc,
    const float* __restrict__ bc, float* __restrict__ P)
{
  __shared__ __align__(16) u16 As[128 * 32];
  __shared__ __align__(16) u16 Bs[128 * 32];
  int t = threadIdx.x;
  int bm = (blockIdx.x / 3) * 128;
  int bn = (blockIdx.x % 3) * 128;
  int lane = t & 63, w = t >> 6;
  int wm = (w >> 1) * 64, wn = (w & 1) * 64;

  f32x4 acc[4][4];
  for (int i = 0; i < 4; i++)
    for (int j = 0; j < 4; j++)
      for (int r = 0; r < 4; r++) acc[i][j][r] = 0.f;

  int mrow = lane & 15, q = lane >> 4;

  for (int kk = 0; kk < 320; kk += 32) {
    #pragma unroll
    for (int p = 0; p < 2; p++) {
      int idx = t + p * 256;
      int row = idx >> 2, ch = idx & 3;
      *(uint4*)&As[idx * 8] =
          *(const uint4*)&praw[(size_t)(bm + row) * 320 + kk + ch * 8];
      *(uint4*)&Bs[idx * 8] =
          *(const uint4*)&Wc[(size_t)(bn + row) * 320 + kk + ch * 8];
    }
    __syncthreads();

    bf16x8 af[4], bfr[4];
    #pragma unroll
    for (int i = 0; i < 4; i++)
      af[i] = *(const bf16x8*)&As[(wm + i * 16 + mrow) * 32 + q * 8];
    #pragma unroll
    for (int j = 0; j < 4; j++)
      bfr[j] = *(const bf16x8*)&Bs[(wn + j * 16 + mrow) * 32 + q * 8];
    #pragma unroll
    for (int i = 0; i < 4; i++)
      #pragma unroll
      for (int j = 0; j < 4; j++)
        acc[i][j] = __builtin_amdgcn_mfma_f32_16x16x32_bf16(
            af[i], bfr[j], acc[i][j], 0, 0, 0);
    __syncthreads();
  }

  #pragma unroll
  for (int i = 0; i < 4; i++)
    #pragma unroll
    for (int j = 0; j < 4; j++) {
      int col = bn + wn + j * 16 + (lane & 15);
      if (col >= 300) continue;
      int rb = bm + wm + i * 16 + (lane >> 4) * 4;
      #pragma unroll
      for (int r = 0; r < 4; r++)
        P[(size_t)(rb + r) * 300 + col] = acc[i][j][r] + bc[col];
    }
}

// ---------------------------------------------------------------------------
extern "C" void kernel_launch(void* const* d_in, const int* in_sizes, int n_in,
                              void* d_out, int out_size, void* d_ws,
                              size_t ws_size, hipStream_t stream)
{
  const float* wv      = (const float*)d_in[0];   // [30000,300] f32
  const float* Wf      = (const float*)d_in[1];   // [300,2048]  f32
  const float* bf      = (const float*)d_in[2];   // [300]       f32
  const float* Wp      = (const float*)d_in[3];   // [300,300]   f32
  const float* bp      = (const float*)d_in[4];   // [300]       f32
  const float* Wm      = (const float*)d_in[5];   // [300,300]   f32
  const float* bm      = (const float*)d_in[6];   // [300]       f32
  const float* feature = (const float*)d_in[7];   // [256,64,2048] f32
  const int*   query   = (const int*)d_in[8];     // [256,32,12]
  const int*   label   = (const int*)d_in[9];     // [256,64]

  float* out   = (float*)d_out;     // f32 output
  float* p_out = out;               // p_emb: 8192*300
  float* k_out = out + 2457600;     // k_emb: 16384*300

  char* ws = (char*)d_ws;
  int full = ws_size >= (size_t)35175936;
  u16 *wv16 = 0, *kemb16 = 0, *praw, *Wc;
  float* bc;
  if (full) {
    wv16   = (u16*)ws;                    // 30000*320*2 = 19,200,000
    kemb16 = (u16*)(ws + 19200000);       // 16384*320*2 = 10,485,760
    praw   = (u16*)(ws + 29685760);       //  8192*320*2 =  5,242,880
    Wc     = (u16*)(ws + 34928640);       //   384*320*2 =    245,760
    bc     = (float*)(ws + 35174400);     //   384*4
  } else {
    praw   = (u16*)ws;
    Wc     = (u16*)(ws + 5242880);
    bc     = (float*)(ws + 5488640);
  }

  prep_wc<<<240, 256, 0, stream>>>(Wp, bp, Wm, bm, Wc, bc);
  if (full)
    prep_wv16<<<18750, 256, 0, stream>>>(wv, wv16);

  gemm0_kernel<<<384, 256, 0, stream>>>(feature, Wf, bf, label, wv,
                                        k_out, kemb16);

  if (full)
    attn_kernel<1><<<512, 256, 0, stream>>>(wv, wv16, query, k_out,
                                            kemb16, praw);
  else
    attn_kernel<0><<<512, 256, 0, stream>>>(wv, wv16, query, k_out,
                                            kemb16, praw);

  proj_kernel<<<192, 256, 0, stream>>>(praw, Wc, bc, p_out);
}

// Round 8
// 374.342 us; speedup vs baseline: 1.9262x; 1.0063x over previous
//
#include <hip/hip_runtime.h>

typedef unsigned short u16;
typedef unsigned int u32;
typedef __bf16 bf16x8 __attribute__((ext_vector_type(8)));
typedef float f32x4 __attribute__((ext_vector_type(4)));

#if defined(__has_builtin)
#  if __has_builtin(__builtin_amdgcn_cvt_pk_bf16_f32)
#    define PK_BF16 1
#  endif
#endif

__device__ __forceinline__ u16 f2bu(float f){
  u32 u = __float_as_uint(f);
  return (u16)((u + 0x7fffu + ((u >> 16) & 1u)) >> 16);
}
__device__ __forceinline__ float b2f(u16 u){
  union { float f; u32 i; } v; v.i = ((u32)u) << 16; return v.f;
}
__device__ __forceinline__ u32 pkbf(float a, float b){
#ifdef PK_BF16
  typedef __bf16 bf16x2 __attribute__((ext_vector_type(2)));
  union { bf16x2 h; u32 u; } c;
  c.h = __builtin_amdgcn_cvt_pk_bf16_f32(a, b);
  return c.u;
#else
  return (u32)f2bu(a) | ((u32)f2bu(b) << 16);
#endif
}
// async global->LDS, 16B per lane; LDS dest = wave-uniform base + lane*16
__device__ __forceinline__ void glds16(const u16* g, u16* l){
  __builtin_amdgcn_global_load_lds(
      (const __attribute__((address_space(1))) void*)g,
      (__attribute__((address_space(3))) void*)l, 16, 0, 0);
}

// ---------------------------------------------------------------------------
// prep_wc: Wc[384][320] bf16 = Wp + 1e-5*Wm (zero padded), bc[384] f32
// ---------------------------------------------------------------------------
__global__ __launch_bounds__(256) void prep_wc(
    const float* __restrict__ Wp, const float* __restrict__ bp,
    const float* __restrict__ Wm, const float* __restrict__ bm,
    u16* __restrict__ Wc, float* __restrict__ bc)
{
  int idx = blockIdx.x * 256 + threadIdx.x;   // bf16-pair index
  if (idx < 384 * 160) {
    int n = idx / 160, k = (idx % 160) * 2;
    float v0 = 0.f, v1 = 0.f;
    if (n < 300 && k < 300) {
      v0 = Wp[n * 300 + k]     + 1e-5f * Wm[n * 300 + k];
      v1 = Wp[n * 300 + k + 1] + 1e-5f * Wm[n * 300 + k + 1];
    }
    ((u32*)Wc)[idx] = pkbf(v0, v1);
    if (idx < 384) bc[idx] = (idx < 300) ? bp[idx] + 1e-5f * bm[idx] : 0.f;
  }
}

// ---------------------------------------------------------------------------
// prep_wv16: wv16[30000][320] bf16 copy of wv (cols 300..319 zero)
// ---------------------------------------------------------------------------
__global__ __launch_bounds__(256) void prep_wv16(
    const float* __restrict__ wv, u16* __restrict__ wv16)
{
  int idx = blockIdx.x * 256 + threadIdx.x;   // pair index
  if (idx < 30000 * 160) {
    int row = idx / 160, k = (idx % 160) * 2;
    float v0 = 0.f, v1 = 0.f;
    if (k < 300) {
      v0 = wv[(size_t)row * 300 + k];
      v1 = wv[(size_t)row * 300 + k + 1];
    }
    ((u32*)wv16)[idx] = pkbf(v0, v1);
  }
}

// ---------------------------------------------------------------------------
// prep_f16: flat f32 -> bf16 (4 elems/thread)
// ---------------------------------------------------------------------------
__global__ __launch_bounds__(256) void prep_f16(
    const float* __restrict__ src, u16* __restrict__ dst, int n4)
{
  int i = blockIdx.x * 256 + threadIdx.x;
  if (i < n4) {
    float4 v = ((const float4*)src)[i];
    uint2 o; o.x = pkbf(v.x, v.y); o.y = pkbf(v.z, v.w);
    ((uint2*)dst)[i] = o;
  }
}

// ---------------------------------------------------------------------------
// prep_wf16: Wf[300][2048] f32 -> Wf16[384][2048] bf16 (rows 300..383 zero)
// ---------------------------------------------------------------------------
__global__ __launch_bounds__(256) void prep_wf16(
    const float* __restrict__ Wf, u16* __restrict__ Wf16)
{
  int i = blockIdx.x * 256 + threadIdx.x;   // pair index, 384*1024 total
  if (i < 384 * 1024) {
    int row = i >> 10, c2 = (i & 1023) * 2;
    float v0 = 0.f, v1 = 0.f;
    if (row < 300) {
      v0 = Wf[(size_t)row * 2048 + c2];
      v1 = Wf[(size_t)row * 2048 + c2 + 1];
    }
    ((u32*)Wf16)[i] = pkbf(v0, v1);
  }
}

// ---------------------------------------------------------------------------
// gemm0: k_emb[m][n] = sum_k feature[m][k]*Wf[n][k] + bf[n] + wv[label[m]][n]
// -> f32 k_out (+ bf16 kemb16).  128x128 tile, 4 waves, 16x16x32 bf16 MFMA.
// GLDS=1: bf16 sources (Af16/Bf16, B zero-padded to 384 rows), async
//         global_load_lds staging.  GLDS=0: f32 sources, cvt in staging.
// ---------------------------------------------------------------------------
template <int GLDS>
__global__ __launch_bounds__(256) void gemm0_kernel(
    const float* __restrict__ A, const float* __restrict__ B,
    const u16* __restrict__ Af16, const u16* __restrict__ Bf16,
    const float* __restrict__ bias,
    const int* __restrict__ label, const float* __restrict__ wv,
    float* __restrict__ C, u16* __restrict__ kemb16)
{
  __shared__ __align__(16) u16 As[128 * 32];
  __shared__ __align__(16) u16 Bs[128 * 32];
  const int lda = 2048, K = 2048, nbn = 3, nsrc = 300;
  int t = threadIdx.x;
  int bm = (blockIdx.x / nbn) * 128;
  int bn = (blockIdx.x % nbn) * 128;
  int lane = t & 63, w = t >> 6;
  int wm = (w >> 1) * 64, wn = (w & 1) * 64;

  f32x4 acc[4][4];
  for (int i = 0; i < 4; i++)
    for (int j = 0; j < 4; j++)
      for (int r = 0; r < 4; r++) acc[i][j][r] = 0.f;

  int mrow = lane & 15, q = lane >> 4;

  for (int kk = 0; kk < K; kk += 32) {
    if (GLDS) {
      // wave w stages rows [w*32, w*32+32) of As and Bs (2 glds each)
      int r0 = w * 32;
      int rl = lane >> 2, ch = lane & 3;
      #pragma unroll
      for (int p = 0; p < 2; p++) {
        int row = r0 + p * 16 + rl;
        glds16(&Af16[(size_t)(bm + row) * 2048 + kk + ch * 8],
               &As[(r0 + p * 16) * 32]);
        glds16(&Bf16[(size_t)(bn + row) * 2048 + kk + ch * 8],
               &Bs[(r0 + p * 16) * 32]);
      }
    } else {
      #pragma unroll
      for (int p = 0; p < 2; p++) {
        int idx = t + p * 256;
        int row = idx >> 2, ch = idx & 3;
        int brow = bn + row;
        if (brow >= nsrc) brow = 0;  // clamp; masked at store
        const float4* ap = (const float4*)&A[(size_t)(bm + row) * lda + kk + ch * 8];
        float4 a0 = ap[0], a1 = ap[1];
        const float4* bpp = (const float4*)&B[(size_t)brow * lda + kk + ch * 8];
        float4 b0 = bpp[0], b1 = bpp[1];
        union { u32 u[4]; uint4 v; } pa, pb;
        pa.u[0] = pkbf(a0.x, a0.y); pa.u[1] = pkbf(a0.z, a0.w);
        pa.u[2] = pkbf(a1.x, a1.y); pa.u[3] = pkbf(a1.z, a1.w);
        pb.u[0] = pkbf(b0.x, b0.y); pb.u[1] = pkbf(b0.z, b0.w);
        pb.u[2] = pkbf(b1.x, b1.y); pb.u[3] = pkbf(b1.z, b1.w);
        *(uint4*)&As[idx * 8] = pa.v;
        *(uint4*)&Bs[idx * 8] = pb.v;
      }
    }
    __syncthreads();

    bf16x8 af[4], bfr[4];
    #pragma unroll
    for (int i = 0; i < 4; i++)
      af[i] = *(const bf16x8*)&As[(wm + i * 16 + mrow) * 32 + q * 8];
    #pragma unroll
    for (int j = 0; j < 4; j++)
      bfr[j] = *(const bf16x8*)&Bs[(wn + j * 16 + mrow) * 32 + q * 8];
    #pragma unroll
    for (int i = 0; i < 4; i++)
      #pragma unroll
      for (int j = 0; j < 4; j++)
        acc[i][j] = __builtin_amdgcn_mfma_f32_16x16x32_bf16(
            af[i], bfr[j], acc[i][j], 0, 0, 0);
    __syncthreads();
  }

  // epilogue: C/D layout col=lane&15, row=(lane>>4)*4+reg
  #pragma unroll
  for (int i = 0; i < 4; i++)
    #pragma unroll
    for (int j = 0; j < 4; j++) {
      int col = bn + wn + j * 16 + (lane & 15);
      int rb = bm + wm + i * 16 + (lane >> 4) * 4;
      #pragma unroll
      for (int r = 0; r < 4; r++) {
        int m = rb + r;
        if (col < 300) {
          float v = acc[i][j][r];
          v += bias[col] + wv[(size_t)label[m] * 300 + col];
          C[(size_t)m * 300 + col] = v;
          if (kemb16) kemb16[(size_t)m * 320 + col] = f2bu(v);
        } else if (kemb16 && col < 320) {
          kemb16[(size_t)m * 320 + col] = 0;
        }
      }
    }
}

// ---------------------------------------------------------------------------
// attn (MFMA): block = (b, half of 16 y) -> 192 qwords x 64 keys, K=320.
// ke bf16 in LDS stride 344; A frags straight from wv16 (FULL) with depth-1
// prefetch, or from wv f32 (fallback). Softmax via shfl (1/sum-exp identity),
// word-softmax/5, vectorized p_raw -> praw bf16 [row][320].
// ---------------------------------------------------------------------------
#define KES 344
template <int FULL>
__global__ __launch_bounds__(256) void attn_kernel(
    const float* __restrict__ wv, const u16* __restrict__ wv16,
    const int* __restrict__ query,
    const float* __restrict__ kout, const u16* __restrict__ kemb16,
    u16* __restrict__ praw)
{
  __shared__ __align__(16) u16 ke[64 * KES];
  __shared__ __align__(16) int qoff[192];
  __shared__ __align__(16) float awd[192];
  __shared__ __align__(16) float wt[192];

  int blk = blockIdx.x, b = blk >> 1, bh = blk & 1;
  int t = threadIdx.x;
  int lane = t & 63, w = t >> 6;

  if (FULL) {
    for (int i = t; i < 2560; i += 256) {          // uint4 chunks of 8 cols
      int row = i / 40, ch = i % 40;
      *(uint4*)&ke[row * KES + ch * 8] =
          *(const uint4*)&kemb16[(size_t)(b * 64 + row) * 320 + ch * 8];
    }
  } else {
    for (int i = t; i < 4800; i += 256) {          // float4 chunks of 4 cols
      int row = i / 75, c4 = i % 75;
      float4 v = *(const float4*)&kout[(size_t)(b * 64 + row) * 300 + c4 * 4];
      *(u32*)&ke[row * KES + c4 * 4]     = pkbf(v.x, v.y);
      *(u32*)&ke[row * KES + c4 * 4 + 2] = pkbf(v.z, v.w);
    }
    for (int i = t; i < 640; i += 256) {           // zero cols 300..319
      int row = i / 10, c2 = i % 10;
      *(u32*)&ke[row * KES + 300 + c2 * 2] = 0;
    }
  }
  if (t < 192)
    qoff[t] = query[b * 384 + bh * 192 + t] * (FULL ? 320 : 300);
  __syncthreads();

  int mrow = lane & 15, q = lane >> 4;
  f32x4 acc[3][4];
  #pragma unroll
  for (int i = 0; i < 3; i++)
    #pragma unroll
    for (int j = 0; j < 4; j++)
      #pragma unroll
      for (int r = 0; r < 4; r++) acc[i][j][r] = 0.f;

  int base[3];
  #pragma unroll
  for (int i = 0; i < 3; i++) base[i] = qoff[w * 48 + i * 16 + mrow];
  int keb = mrow * KES + q * 8;

  bf16x8 afn[3];
  #pragma unroll
  for (int i = 0; i < 3; i++) {
    if (FULL)
      afn[i] = *(const bf16x8*)&wv16[(size_t)base[i] + q * 8];
  }

  for (int k0 = 0; k0 < 320; k0 += 32) {
    bf16x8 af[3], bfr[4];
    #pragma unroll
    for (int i = 0; i < 3; i++) {
      if (FULL) {
        af[i] = afn[i];
        if (k0 + 32 < 320)      // depth-1 prefetch
          afn[i] = *(const bf16x8*)&wv16[(size_t)base[i] + k0 + 32 + q * 8];
      } else {
        int cs = k0 + q * 8;
        union { u32 u[4]; bf16x8 h; } c;
        if (cs + 8 <= 300) {
          const float4* p = (const float4*)&wv[(size_t)base[i] + cs];
          float4 x = p[0], y = p[1];
          c.u[0] = pkbf(x.x, x.y); c.u[1] = pkbf(x.z, x.w);
          c.u[2] = pkbf(y.x, y.y); c.u[3] = pkbf(y.z, y.w);
        } else if (cs < 300) {   // cs == 296
          float4 x = *(const float4*)&wv[(size_t)base[i] + 296];
          c.u[0] = pkbf(x.x, x.y); c.u[1] = pkbf(x.z, x.w);
          c.u[2] = 0; c.u[3] = 0;
        } else {
          c.u[0] = 0; c.u[1] = 0; c.u[2] = 0; c.u[3] = 0;
        }
        af[i] = c.h;
      }
    }
    #pragma unroll
    for (int j = 0; j < 4; j++)
      bfr[j] = *(const bf16x8*)&ke[j * 16 * KES + keb + k0];
    #pragma unroll
    for (int i = 0; i < 3; i++)
      #pragma unroll
      for (int j = 0; j < 4; j++)
        acc[i][j] = __builtin_amdgcn_mfma_f32_16x16x32_bf16(
            af[i], bfr[j], acc[i][j], 0, 0, 0);
  }

  // per-word softmax-over-keys: a_w = 1/sum_k exp(scale*(att-max))
  const float scale = 0.05773502691896258f;   // 1/sqrt(300)
  #pragma unroll
  for (int i = 0; i < 3; i++)
    #pragma unroll
    for (int r = 0; r < 4; r++) {
      float mx = fmaxf(fmaxf(acc[i][0][r], acc[i][1][r]),
                       fmaxf(acc[i][2][r], acc[i][3][r]));
      #pragma unroll
      for (int d = 1; d < 16; d <<= 1)
        mx = fmaxf(mx, __shfl_xor(mx, d));
      float se = 0.f;
      #pragma unroll
      for (int j = 0; j < 4; j++)
        se += __expf((acc[i][j][r] - mx) * scale);
      #pragma unroll
      for (int d = 1; d < 16; d <<= 1)
        se += __shfl_xor(se, d);
      if (mrow == 0) {
        int wl = w * 48 + i * 16 + q * 4 + r;
        awd[wl] = (qoff[wl] == 0) ? -3.402823466e38f : (1.0f / se);
      }
    }
  __syncthreads();

  // per-y softmax over 12 words, /5
  if (t < 16) {
    int yb = t * 12;
    float m2 = -3.402823466e38f;
    for (int i = 0; i < 12; i++) m2 = fmaxf(m2, awd[yb + i]);
    float e[12], s2 = 0.f;
    for (int i = 0; i < 12; i++) { e[i] = __expf(awd[yb + i] - m2); s2 += e[i]; }
    float inv = 0.2f / s2;
    for (int i = 0; i < 12; i++) wt[yb + i] = e[i] * inv;
  }
  __syncthreads();

  // p_raw: wave w -> 4 y's
  #pragma unroll
  for (int yy = 0; yy < 4; yy++) {
    int yl = w * 4 + yy;
    int row = b * 32 + bh * 16 + yl;
    if (FULL) {
      if (lane < 40) {     // lane covers 8 cols; 40*8 = 320
        float s[8];
        #pragma unroll
        for (int e = 0; e < 8; e++) s[e] = 0.f;
        for (int i = 0; i < 12; i++) {
          float g = wt[yl * 12 + i];
          union { uint4 v; u16 h[8]; } qv;
          qv.v = *(const uint4*)&wv16[(size_t)qoff[yl * 12 + i] + lane * 8];
          #pragma unroll
          for (int e = 0; e < 8; e++) s[e] += g * b2f(qv.h[e]);
        }
        union { uint4 v; u16 h[8]; } o;
        #pragma unroll
        for (int e = 0; e < 8; e++) o.h[e] = f2bu(s[e]);
        *(uint4*)&praw[(size_t)row * 320 + lane * 8] = o.v;
      }
    } else {
      #pragma unroll
      for (int c = 0; c < 5; c++) {
        int d = c * 64 + lane;
        float s = 0.f;
        if (d < 300)
          for (int i = 0; i < 12; i++)
            s += wt[yl * 12 + i] * wv[(size_t)qoff[yl * 12 + i] + d];
        praw[(size_t)row * 320 + d] = f2bu(s);
      }
    }
  }
}

// ---------------------------------------------------------------------------
// proj (MFMA + glds): p_emb[8192][300] = praw(bf16) @ Wc(bf16)^T + bc -> f32
// ---------------------------------------------------------------------------
__global__ __launch_bounds__(256) void proj_kernel(
    const u16* __restrict__ praw, const u16* __restrict__ Wc,
    const float* __restrict__ bc, float* __restrict__ P)
{
  __shared__ __align__(16) u16 As[128 * 32];
  __shared__ __align__(16) u16 Bs[128 * 32];
  int t = threadIdx.x;
  int bm = (blockIdx.x / 3) * 128;
  int bn = (blockIdx.x % 3) * 128;
  int lane = t & 63, w = t >> 6;
  int wm = (w >> 1) * 64, wn = (w & 1) * 64;

  f32x4 acc[4][4];
  for (int i = 0; i < 4; i++)
    for (int j = 0; j < 4; j++)
      for (int r = 0; r < 4; r++) acc[i][j][r] = 0.f;

  int mrow = lane & 15, q = lane >> 4;

  for (int kk = 0; kk < 320; kk += 32) {
    int r0 = w * 32;
    int rl = lane >> 2, ch = lane & 3;
    #pragma unroll
    for (int p = 0; p < 2; p++) {
      int row = r0 + p * 16 + rl;
      glds16(&praw[(size_t)(bm + row) * 320 + kk + ch * 8],
             &As[(r0 + p * 16) * 32]);
      glds16(&Wc[(size_t)(bn + row) * 320 + kk + ch * 8],
             &Bs[(r0 + p * 16) * 32]);
    }
    __syncthreads();

    bf16x8 af[4], bfr[4];
    #pragma unroll
    for (int i = 0; i < 4; i++)
      af[i] = *(const bf16x8*)&As[(wm + i * 16 + mrow) * 32 + q * 8];
    #pragma unroll
    for (int j = 0; j < 4; j++)
      bfr[j] = *(const bf16x8*)&Bs[(wn + j * 16 + mrow) * 32 + q * 8];
    #pragma unroll
    for (int i = 0; i < 4; i++)
      #pragma unroll
      for (int j = 0; j < 4; j++)
        acc[i][j] = __builtin_amdgcn_mfma_f32_16x16x32_bf16(
            af[i], bfr[j], acc[i][j], 0, 0, 0);
    __syncthreads();
  }

  #pragma unroll
  for (int i = 0; i < 4; i++)
    #pragma unroll
    for (int j = 0; j < 4; j++) {
      int col = bn + wn + j * 16 + (lane & 15);
      if (col >= 300) continue;
      int rb = bm + wm + i * 16 + (lane >> 4) * 4;
      #pragma unroll
      for (int r = 0; r < 4; r++)
        P[(size_t)(rb + r) * 300 + col] = acc[i][j][r] + bc[col];
    }
}

// ---------------------------------------------------------------------------
extern "C" void kernel_launch(void* const* d_in, const int* in_sizes, int n_in,
                              void* d_out, int out_size, void* d_ws,
                              size_t ws_size, hipStream_t stream)
{
  const float* wv      = (const float*)d_in[0];   // [30000,300] f32
  const float* Wf      = (const float*)d_in[1];   // [300,2048]  f32
  const float* bf      = (const float*)d_in[2];   // [300]       f32
  const float* Wp      = (const float*)d_in[3];   // [300,300]   f32
  const float* bp      = (const float*)d_in[4];   // [300]       f32
  const float* Wm      = (const float*)d_in[5];   // [300,300]   f32
  const float* bm      = (const float*)d_in[6];   // [300]       f32
  const float* feature = (const float*)d_in[7];   // [256,64,2048] f32
  const int*   query   = (const int*)d_in[8];     // [256,32,12]
  const int*   label   = (const int*)d_in[9];     // [256,64]

  float* out   = (float*)d_out;     // f32 output
  float* p_out = out;               // p_emb: 8192*300
  float* k_out = out + 2457600;     // k_emb: 16384*300

  char* ws = (char*)d_ws;
  // T2 layout:
  //   feature16:          0  (67,108,864)
  //   wv16:      67,108,864  (19,200,000)
  //   kemb16:    86,308,864  (10,485,760)
  //   praw:      96,794,624  ( 5,242,880)
  //   Wc:       102,037,504  (   245,760)
  //   Wf16:     102,283,264  ( 1,572,864)
  //   bc:       103,856,128  (     1,536)
  int t2 = ws_size >= (size_t)103857664;
  int t1 = ws_size >= (size_t)35175936;
  u16 *f16 = 0, *wf16 = 0, *wv16 = 0, *kemb16 = 0, *praw, *Wc;
  float* bc;
  if (t2) {
    f16    = (u16*)ws;
    wv16   = (u16*)(ws + 67108864);
    kemb16 = (u16*)(ws + 86308864);
    praw   = (u16*)(ws + 96794624);
    Wc     = (u16*)(ws + 102037504);
    wf16   = (u16*)(ws + 102283264);
    bc     = (float*)(ws + 103856128);
  } else if (t1) {
    wv16   = (u16*)ws;                    // 19,200,000
    kemb16 = (u16*)(ws + 19200000);       // 10,485,760
    praw   = (u16*)(ws + 29685760);       //  5,242,880
    Wc     = (u16*)(ws + 34928640);       //    245,760
    bc     = (float*)(ws + 35174400);
  } else {
    praw   = (u16*)ws;
    Wc     = (u16*)(ws + 5242880);
    bc     = (float*)(ws + 5488640);
  }

  prep_wc<<<240, 256, 0, stream>>>(Wp, bp, Wm, bm, Wc, bc);
  if (t1 || t2)
    prep_wv16<<<18750, 256, 0, stream>>>(wv, wv16);
  if (t2) {
    prep_f16<<<32768, 256, 0, stream>>>(feature, f16, 8388608);
    prep_wf16<<<1536, 256, 0, stream>>>(Wf, wf16);
    gemm0_kernel<1><<<384, 256, 0, stream>>>(feature, Wf, f16, wf16, bf,
                                             label, wv, k_out, kemb16);
  } else {
    gemm0_kernel<0><<<384, 256, 0, stream>>>(feature, Wf, 0, 0, bf,
                                             label, wv, k_out, kemb16);
  }

  if (t1 || t2)
    attn_kernel<1><<<512, 256, 0, stream>>>(wv, wv16, query, k_out,
                                            kemb16, praw);
  else
    attn_kernel<0><<<512, 256, 0, stream>>>(wv, wv16, query, k_out,
                                            kemb16, praw);

  proj_kernel<<<192, 256, 0, stream>>>(praw, Wc, bc, p_out);
}